// Round 14
// baseline (143.289 us; speedup 1.0000x reference)
//
#include <hip/hip_runtime.h>

#define D_    2560
#define NH_   8
#define NKV_  4
#define HD_   256
#define FFN_  10240
#define QD_   2048
#define CTX_  4096
#define EPSF  1e-6f
#define ACH   128   // attention chunks per kv head (32 rows each)

typedef float f4 __attribute__((ext_vector_type(4)));

__device__ __forceinline__ float wave_red_sum(float v) {
#pragma unroll
    for (int o = 32; o > 0; o >>= 1) v += __shfl_down(v, o, 64);
    return v;
}

// butterfly: result in ALL lanes
__device__ __forceinline__ float wave_red_sum_b(float v) {
#pragma unroll
    for (int o = 32; o > 0; o >>= 1) v += __shfl_xor(v, o, 64);
    return v;
}

template <int NW>
__device__ __forceinline__ float block_red_sum(float v) {
    __shared__ float s[NW];
    __shared__ float tot;
    int lane = threadIdx.x & 63, w = threadIdx.x >> 6;
    v = wave_red_sum(v);
    if (lane == 0) s[w] = v;
    __syncthreads();
    if (threadIdx.x == 0) {
        float t = 0.f;
#pragma unroll
        for (int i = 0; i < NW; i++) t += s[i];
        tot = t;
    }
    __syncthreads();
    return tot;
}

template <int NW>
__device__ __forceinline__ float block_red_max(float v) {
    __shared__ float s[NW];
    __shared__ float tot;
    int lane = threadIdx.x & 63, w = threadIdx.x >> 6;
#pragma unroll
    for (int o = 32; o > 0; o >>= 1) v = fmaxf(v, __shfl_down(v, o, 64));
    if (lane == 0) s[w] = v;
    __syncthreads();
    if (threadIdx.x == 0) {
        float t = -3e38f;
#pragma unroll
        for (int i = 0; i < NW; i++) t = fmaxf(t, s[i]);
        tot = t;
    }
    __syncthreads();
    return tot;
}

// ---- Wq GEMV with inline rmsnorm(x, w_in) ----
__global__ __launch_bounds__(256) void k_wq_fused(const float* __restrict__ Wq,
                                                  const float* __restrict__ x,
                                                  const float* __restrict__ w_in,
                                                  float* __restrict__ qraw) {
    int lane = threadIdx.x & 63;
    int row = (blockIdx.x * 256 + threadIdx.x) >> 6;
    const f4* X = (const f4*)x + lane;
    const f4* WI = (const f4*)w_in + lane;
    f4 xx[10], wi[10];
#pragma unroll
    for (int k = 0; k < 10; k++) xx[k] = X[k * 64];
#pragma unroll
    for (int k = 0; k < 10; k++) wi[k] = WI[k * 64];
    const f4* Wr = (const f4*)Wq + (size_t)row * 640 + lane;
    f4 wv[10];
#pragma unroll
    for (int k = 0; k < 10; k++) wv[k] = __builtin_nontemporal_load(Wr + k * 64);
    float ss = 0.f;
#pragma unroll
    for (int k = 0; k < 10; k++)
        ss += xx[k].x * xx[k].x + xx[k].y * xx[k].y + xx[k].z * xx[k].z + xx[k].w * xx[k].w;
    ss = wave_red_sum_b(ss);
    float rs = rsqrtf(ss / (float)D_ + EPSF);
    float acc = 0.f;
#pragma unroll
    for (int k = 0; k < 10; k++) {
        f4 hh = xx[k] * rs * (1.f + wi[k]);
        acc += wv[k].x * hh.x + wv[k].y * hh.y + wv[k].z * hh.z + wv[k].w * hh.w;
    }
    acc = wave_red_sum(acc);
    if (lane == 0) qraw[row] = acc;
}

// ---- GEMV: x preloaded before W burst, in-order consumption ----
template <int CPL>
__global__ __launch_bounds__(256) void k_gemv_row(const float* __restrict__ W,
                                                  const float* __restrict__ x,
                                                  float* __restrict__ y) {
    int lane = threadIdx.x & 63;
    int row = (blockIdx.x * 256 + threadIdx.x) >> 6;
    const f4* X = (const f4*)x + lane;
    f4 xx[CPL];
#pragma unroll
    for (int k = 0; k < CPL; k++) xx[k] = X[k * 64];
    const f4* Wr = (const f4*)W + (size_t)row * (CPL * 64) + lane;
    f4 wv[CPL];
#pragma unroll
    for (int k = 0; k < CPL; k++) wv[k] = __builtin_nontemporal_load(Wr + k * 64);
    float acc = 0.f;
#pragma unroll
    for (int k = 0; k < CPL; k++)
        acc += wv[k].x * xx[k].x + wv[k].y * xx[k].y + wv[k].z * xx[k].z + wv[k].w * xx[k].w;
    acc = wave_red_sum(acc);
    if (lane == 0) y[row] = acc;
}

// ---- PROBE-SHAPED GeGLU partials: each wave loads ONE 1KB chunk from each
// of 8 rows spaced 2560 rows (~26 MB) apart — 8 independent far-apart
// streams in flight, like the 6 TB/s probe.  part[c*20480 + row] = dot. ----
__global__ __launch_bounds__(256) void k_gg_probe(const float* __restrict__ Wg,
                                                  const float* __restrict__ Wu,
                                                  const float* __restrict__ h,
                                                  float* __restrict__ part) {
    int lane = threadIdx.x & 63;
    int gw = (blockIdx.x * 256 + threadIdx.x) >> 6;   // 0..25599
    int c = gw % 10;                                   // column chunk
    int rb = gw - c * 1;  rb = gw / 10;                // row base 0..2559
    f4 xx = ((const f4*)h)[c * 64 + lane];
    f4 wv[8];
#pragma unroll
    for (int j = 0; j < 8; j++) {
        int r = rb + j * 2560;                         // 0..20479 virtual row
        const f4* p = (r < FFN_) ? (const f4*)Wg + (size_t)r * 640
                                 : (const f4*)Wu + (size_t)(r - FFN_) * 640;
        wv[j] = __builtin_nontemporal_load(p + c * 64 + lane);
    }
    float d[8];
#pragma unroll
    for (int j = 0; j < 8; j++)
        d[j] = wv[j].x * xx.x + wv[j].y * xx.y + wv[j].z * xx.z + wv[j].w * xx.w;
#pragma unroll
    for (int o = 32; o > 0; o >>= 1) {
#pragma unroll
        for (int j = 0; j < 8; j++) d[j] += __shfl_down(d[j], o, 64);
    }
    if (lane == 0) {
#pragma unroll
        for (int j = 0; j < 8; j++) part[c * 20480 + rb + j * 2560] = d[j];
    }
}

// ---- gu[i] = gelu(sum_c part[c][i]) * (sum_c part[c][FFN+i]) ----
__global__ __launch_bounds__(256) void k_gelu_fuse(const float* __restrict__ part,
                                                   float* __restrict__ gu) {
    int i = blockIdx.x * 256 + threadIdx.x;
    float g = 0.f, u = 0.f;
#pragma unroll
    for (int c = 0; c < 10; c++) {
        g += part[c * 20480 + i];
        u += part[c * 20480 + FFN_ + i];
    }
    float tt = tanhf(0.7978845608028654f * (g + 0.044715f * g * g * g));
    gu[i] = 0.5f * g * (1.f + tt) * u;
}

// ---- PROBE-SHAPED Wd partials: chunk c of 8 rows spaced 320 rows
// (~13 MB) apart.  part[c*2560 + row] = dot. ----
__global__ __launch_bounds__(256) void k_wd_probe(const float* __restrict__ Wd,
                                                  const float* __restrict__ gu,
                                                  float* __restrict__ part) {
    int lane = threadIdx.x & 63;
    int gw = (blockIdx.x * 256 + threadIdx.x) >> 6;   // 0..12799
    int c = gw % 40;                                   // column chunk
    int rb = gw / 40;                                  // 0..319
    f4 xx = ((const f4*)gu)[c * 64 + lane];
    f4 wv[8];
#pragma unroll
    for (int j = 0; j < 8; j++) {
        int r = rb + j * 320;
        wv[j] = __builtin_nontemporal_load((const f4*)Wd + (size_t)r * 2560 + c * 64 + lane);
    }
    float d[8];
#pragma unroll
    for (int j = 0; j < 8; j++)
        d[j] = wv[j].x * xx.x + wv[j].y * xx.y + wv[j].z * xx.z + wv[j].w * xx.w;
#pragma unroll
    for (int o = 32; o > 0; o >>= 1) {
#pragma unroll
        for (int j = 0; j < 8; j++) d[j] += __shfl_down(d[j], o, 64);
    }
    if (lane == 0) {
#pragma unroll
        for (int j = 0; j < 8; j++) part[c * 2560 + rb + j * 320] = d[j];
    }
}

// out1 = (res?) res + rms(a)*(1+w1);  a[i] = sum_{s<slots} apart[s*pstride+i]
__global__ __launch_bounds__(512) void k_res_rms(const float* __restrict__ res,
                                                 const float* __restrict__ apart,
                                                 int slots, int pstride,
                                                 const float* __restrict__ w1, float* __restrict__ out1,
                                                 const float* __restrict__ w2, float* __restrict__ out2) {
    const int K = D_ / 512;
    int t = threadIdx.x;
    float va[K];
    float ss = 0.f;
#pragma unroll
    for (int k = 0; k < K; k++) {
        int i = t + k * 512;
        float v = 0.f;
        for (int s = 0; s < slots; s++) v += apart[(size_t)s * pstride + i];
        va[k] = v;
        ss += v * v;
    }
    float tot = block_red_sum<8>(ss);
    float rs = rsqrtf(tot / (float)D_ + EPSF);
    float vo[K];
    float ss2 = 0.f;
#pragma unroll
    for (int k = 0; k < K; k++) {
        int i = t + k * 512;
        float r = res ? res[i] : 0.f;
        vo[k] = r + va[k] * rs * (1.f + w1[i]);
        out1[i] = vo[k];
        ss2 += vo[k] * vo[k];
    }
    if (out2) {
        float tot2 = block_red_sum<8>(ss2);
        float rs2 = rsqrtf(tot2 / (float)D_ + EPSF);
#pragma unroll
        for (int k = 0; k < K; k++) {
            int i = t + k * 512;
            out2[i] = vo[k] * rs2 * (1.f + w2[i]);
        }
    }
}

// ---- flash-decode partial: one block per (kvh, 32-row chunk).  512 blocks.
__global__ __launch_bounds__(256) void k_attn_part(const float* __restrict__ Kc,
                                                   const float* __restrict__ V,
                                                   const float* __restrict__ qraw,
                                                   const float* __restrict__ cosv,
                                                   const float* __restrict__ sinv,
                                                   const float* __restrict__ mask,
                                                   float* __restrict__ pm,
                                                   float* __restrict__ pl,
                                                   float* __restrict__ pacc) {
    constexpr int RW = CTX_ / ACH;   // 32 rows per chunk, 8 per wave
    int kvh = blockIdx.x, ch = blockIdx.y;
    int lane = threadIdx.x & 63, w = threadIdx.x >> 6;
    int t = threadIdx.x;
    int h0 = 2 * kvh, h1 = h0 + 1;
    int l0 = ch * RW;
    __shared__ float s0[RW], s1[RW];
    __shared__ f4 pv0[4][64], pv1[4][64];

    const f4* q4 = (const f4*)qraw;
    f4 qr0 = q4[h0 * 64 + lane];
    f4 qr1 = q4[h1 * 64 + lane];
    float n0 = wave_red_sum_b(qr0.x * qr0.x + qr0.y * qr0.y + qr0.z * qr0.z + qr0.w * qr0.w);
    float n1 = wave_red_sum_b(qr1.x * qr1.x + qr1.y * qr1.y + qr1.z * qr1.z + qr1.w * qr1.w);
    f4 qn0 = qr0 * rsqrtf(n0 / (float)HD_ + EPSF);
    f4 qn1 = qr1 * rsqrtf(n1 / (float)HD_ + EPSF);
    f4 p0, p1;
    p0.x = __shfl_xor(qn0.x, 32, 64); p0.y = __shfl_xor(qn0.y, 32, 64);
    p0.z = __shfl_xor(qn0.z, 32, 64); p0.w = __shfl_xor(qn0.w, 32, 64);
    p1.x = __shfl_xor(qn1.x, 32, 64); p1.y = __shfl_xor(qn1.y, 32, 64);
    p1.z = __shfl_xor(qn1.z, 32, 64); p1.w = __shfl_xor(qn1.w, 32, 64);
    f4 rot0 = (lane < 32) ? -p0 : p0;
    f4 rot1 = (lane < 32) ? -p1 : p1;
    f4 cs = ((const f4*)cosv)[lane];
    f4 sn = ((const f4*)sinv)[lane];
    f4 q0 = qn0 * cs + rot0 * sn;
    f4 q1 = qn1 * cs + rot1 * sn;

    const f4* Kb = (const f4*)Kc + ((size_t)kvh * CTX_ + l0 + w * 8) * 64 + lane;
    f4 kk[8];
#pragma unroll
    for (int i = 0; i < 8; i++) kk[i] = Kb[i * 64];
    float d0[8], d1[8];
#pragma unroll
    for (int i = 0; i < 8; i++) {
        d0[i] = kk[i].x * q0.x + kk[i].y * q0.y + kk[i].z * q0.z + kk[i].w * q0.w;
        d1[i] = kk[i].x * q1.x + kk[i].y * q1.y + kk[i].z * q1.z + kk[i].w * q1.w;
    }
#pragma unroll
    for (int o = 32; o > 0; o >>= 1) {
#pragma unroll
        for (int i = 0; i < 8; i++) {
            d0[i] += __shfl_down(d0[i], o, 64);
            d1[i] += __shfl_down(d1[i], o, 64);
        }
    }
    if (lane == 0) {
#pragma unroll
        for (int i = 0; i < 8; i++) {
            float m = mask[l0 + w * 8 + i];
            s0[w * 8 + i] = d0[i] + m;
            s1[w * 8 + i] = d1[i] + m;
        }
    }
    __syncthreads();

    float m0 = block_red_max<4>(t < RW ? s0[t] : -3e38f);
    float m1 = block_red_max<4>(t < RW ? s1[t] : -3e38f);
    float e0 = 0.f, e1 = 0.f;
    if (t < RW) {
        e0 = expf(s0[t] - m0); s0[t] = e0;
        e1 = expf(s1[t] - m1); s1[t] = e1;
    }
    float l0sum = block_red_sum<4>(e0);
    float l1sum = block_red_sum<4>(e1);

    const f4* Vb = (const f4*)V + ((size_t)kvh * CTX_ + l0 + w * 8) * 64 + lane;
    f4 vv[8];
#pragma unroll
    for (int i = 0; i < 8; i++) vv[i] = Vb[i * 64];
    f4 a0 = {0.f, 0.f, 0.f, 0.f}, a1 = {0.f, 0.f, 0.f, 0.f};
#pragma unroll
    for (int i = 0; i < 8; i++) {
        a0 += vv[i] * s0[w * 8 + i];
        a1 += vv[i] * s1[w * 8 + i];
    }
    pv0[w][lane] = a0;
    pv1[w][lane] = a1;
    __syncthreads();
    const float* f0 = (const float*)pv0;
    const float* f1 = (const float*)pv1;
    float r0 = f0[t] + f0[256 + t] + f0[512 + t] + f0[768 + t];
    float r1 = f1[t] + f1[256 + t] + f1[512 + t] + f1[768 + t];
    pacc[((size_t)(h0 * ACH) + ch) * HD_ + t] = r0;
    pacc[((size_t)(h1 * ACH) + ch) * HD_ + t] = r1;
    if (t == 0) {
        pm[h0 * ACH + ch] = m0; pl[h0 * ACH + ch] = l0sum;
        pm[h1 * ACH + ch] = m1; pl[h1 * ACH + ch] = l1sum;
    }
}

// ---- combine: grid = NH_, thread = d ----
__global__ __launch_bounds__(256) void k_attn_comb(const float* __restrict__ pm,
                                                   const float* __restrict__ pl,
                                                   const float* __restrict__ pacc,
                                                   float* __restrict__ a) {
    int h = blockIdx.x, t = threadIdx.x;
    __shared__ float wgt[ACH];
    float M = block_red_max<4>(t < ACH ? pm[h * ACH + t] : -3e38f);
    float lw = 0.f;
    if (t < ACH) {
        float wv = expf(pm[h * ACH + t] - M);
        wgt[t] = wv;
        lw = wv * pl[h * ACH + t];
    }
    float L = block_red_sum<4>(lw);
    float acc = 0.f;
    const float* pb = pacc + (size_t)h * ACH * HD_ + t;
#pragma unroll 8
    for (int c = 0; c < ACH; c++) acc += wgt[c] * pb[(size_t)c * HD_];
    a[h * HD_ + t] = acc / L;
}

extern "C" void kernel_launch(void* const* d_in, const int* in_sizes, int n_in,
                              void* d_out, int out_size, void* d_ws, size_t ws_size,
                              hipStream_t stream) {
    const float* x     = (const float*)d_in[0];
    const float* cosv  = (const float*)d_in[1];
    const float* sinv  = (const float*)d_in[2];
    const float* mask  = (const float*)d_in[3];
    const float* cK    = (const float*)d_in[4];
    const float* cV    = (const float*)d_in[5];
    const float* w_in  = (const float*)d_in[7];
    const float* w_pa  = (const float*)d_in[8];
    const float* w_pf  = (const float*)d_in[9];
    const float* w_pff = (const float*)d_in[10];
    const float* Wq    = (const float*)d_in[11];
    const float* Wo    = (const float*)d_in[12];
    const float* Wg    = (const float*)d_in[13];
    const float* Wu    = (const float*)d_in[14];
    const float* Wd    = (const float*)d_in[15];

    float* ws    = (float*)d_ws;
    float* qraw  = ws;             // 2048
    float* pm    = ws + 2048;      // 1024
    float* pl    = ws + 3072;      // 1024
    float* pacc  = ws + 4096;      // 262144
    float* a     = ws + 266240;    // 2048
    float* ao    = ws + 268288;    // 2560
    float* x2    = ws + 270848;    // 2560
    float* h2    = ws + 273408;    // 2560
    float* gu    = ws + 275968;    // 10240
    float* partg = ws + 286208;    // 10*20480 = 204800
    float* partd = ws + 491008;    // 40*2560 = 102400
    float* out   = (float*)d_out;

    // qraw = rmsnorm(x,w_in) @ Wq.T  (fused)
    k_wq_fused<<<QD_ / 4, 256, 0, stream>>>(Wq, x, w_in, qraw);
    // attention: flash-decode partials + combine
    k_attn_part<<<dim3(NKV_, ACH), 256, 0, stream>>>(cK, cV, qraw, cosv, sinv,
                                                     mask, pm, pl, pacc);
    k_attn_comb<<<NH_, 256, 0, stream>>>(pm, pl, pacc, a);
    // ao = a @ Wo.T
    k_gemv_row<8><<<D_ / 4, 256, 0, stream>>>(Wo, a, ao);
    // x2 = x + rms(ao)*(1+w_pa);  h2 = rms(x2)*(1+w_pf)
    k_res_rms<<<1, 512, 0, stream>>>(x, ao, 1, 0, w_pa, x2, w_pf, h2);
    // g/u partials: probe-shaped 8-stream loads, then gelu fuse
    k_gg_probe<<<2 * FFN_ * 10 / 8 / 4, 256, 0, stream>>>(Wg, Wu, h2, partg);
    k_gelu_fuse<<<FFN_ / 256, 256, 0, stream>>>(partg, gu);
    // ffn partials: probe-shaped
    k_wd_probe<<<D_ * 40 / 8 / 4, 256, 0, stream>>>(Wd, gu, partd);
    // out = x2 + rms(sum partd)*(1+w_pff)
    k_res_rms<<<1, 512, 0, stream>>>(x2, partd, 40, 2560, w_pff, out, nullptr, nullptr);
}

// Round 15
// 94.918 us; speedup vs baseline: 1.5096x; 1.5096x over previous
//
#include <hip/hip_runtime.h>

#define D_    2560
#define NH_   8
#define NKV_  4
#define HD_   256
#define FFN_  10240
#define QD_   2048
#define CTX_  4096
#define EPSF  1e-6f
#define ACH   128   // attention chunks per kv head (32 rows each)

typedef float f4 __attribute__((ext_vector_type(4)));

__device__ __forceinline__ float wave_red_sum(float v) {
#pragma unroll
    for (int o = 32; o > 0; o >>= 1) v += __shfl_down(v, o, 64);
    return v;
}

// butterfly: result in ALL lanes
__device__ __forceinline__ float wave_red_sum_b(float v) {
#pragma unroll
    for (int o = 32; o > 0; o >>= 1) v += __shfl_xor(v, o, 64);
    return v;
}

template <int NW>
__device__ __forceinline__ float block_red_sum(float v) {
    __shared__ float s[NW];
    __shared__ float tot;
    int lane = threadIdx.x & 63, w = threadIdx.x >> 6;
    v = wave_red_sum(v);
    if (lane == 0) s[w] = v;
    __syncthreads();
    if (threadIdx.x == 0) {
        float t = 0.f;
#pragma unroll
        for (int i = 0; i < NW; i++) t += s[i];
        tot = t;
    }
    __syncthreads();
    return tot;
}

template <int NW>
__device__ __forceinline__ float block_red_max(float v) {
    __shared__ float s[NW];
    __shared__ float tot;
    int lane = threadIdx.x & 63, w = threadIdx.x >> 6;
#pragma unroll
    for (int o = 32; o > 0; o >>= 1) v = fmaxf(v, __shfl_down(v, o, 64));
    if (lane == 0) s[w] = v;
    __syncthreads();
    if (threadIdx.x == 0) {
        float t = -3e38f;
#pragma unroll
        for (int i = 0; i < NW; i++) t = fmaxf(t, s[i]);
        tot = t;
    }
    __syncthreads();
    return tot;
}

// ---- Wq GEMV with inline rmsnorm(x, w_in) ----
__global__ __launch_bounds__(256) void k_wq_fused(const float* __restrict__ Wq,
                                                  const float* __restrict__ x,
                                                  const float* __restrict__ w_in,
                                                  float* __restrict__ qraw) {
    int lane = threadIdx.x & 63;
    int row = (blockIdx.x * 256 + threadIdx.x) >> 6;
    const f4* X = (const f4*)x + lane;
    const f4* WI = (const f4*)w_in + lane;
    f4 xx[10], wi[10];
#pragma unroll
    for (int k = 0; k < 10; k++) xx[k] = X[k * 64];
#pragma unroll
    for (int k = 0; k < 10; k++) wi[k] = WI[k * 64];
    const f4* Wr = (const f4*)Wq + (size_t)row * 640 + lane;
    f4 wv[10];
#pragma unroll
    for (int k = 0; k < 10; k++) wv[k] = __builtin_nontemporal_load(Wr + k * 64);
    float ss = 0.f;
#pragma unroll
    for (int k = 0; k < 10; k++)
        ss += xx[k].x * xx[k].x + xx[k].y * xx[k].y + xx[k].z * xx[k].z + xx[k].w * xx[k].w;
    ss = wave_red_sum_b(ss);
    float rs = rsqrtf(ss / (float)D_ + EPSF);
    float acc = 0.f;
#pragma unroll
    for (int k = 0; k < 10; k++) {
        f4 hh = xx[k] * rs * (1.f + wi[k]);
        acc += wv[k].x * hh.x + wv[k].y * hh.y + wv[k].z * hh.z + wv[k].w * hh.w;
    }
    acc = wave_red_sum(acc);
    if (lane == 0) qraw[row] = acc;
}

// ---- GEMV: x preloaded before W burst, in-order consumption ----
template <int CPL>
__global__ __launch_bounds__(256) void k_gemv_row(const float* __restrict__ W,
                                                  const float* __restrict__ x,
                                                  float* __restrict__ y) {
    int lane = threadIdx.x & 63;
    int row = (blockIdx.x * 256 + threadIdx.x) >> 6;
    const f4* X = (const f4*)x + lane;
    f4 xx[CPL];
#pragma unroll
    for (int k = 0; k < CPL; k++) xx[k] = X[k * 64];
    const f4* Wr = (const f4*)W + (size_t)row * (CPL * 64) + lane;
    f4 wv[CPL];
#pragma unroll
    for (int k = 0; k < CPL; k++) wv[k] = __builtin_nontemporal_load(Wr + k * 64);
    float acc = 0.f;
#pragma unroll
    for (int k = 0; k < CPL; k++)
        acc += wv[k].x * xx[k].x + wv[k].y * xx[k].y + wv[k].z * xx[k].z + wv[k].w * xx[k].w;
    acc = wave_red_sum(acc);
    if (lane == 0) y[row] = acc;
}

// ---- GeGLU partials, wd-shaped: each wave streams TWO ADJACENT rows of ONE
// matrix = 20 KB contiguous single-pointer (pairs never straddle Wg/Wu).
// part[2t] , part[2t+1] = dots of virtual rows 2t, 2t+1 with x. ----
__global__ __launch_bounds__(256) void k_gg2(const float* __restrict__ Wg,
                                             const float* __restrict__ Wu,
                                             const float* __restrict__ h,
                                             float* __restrict__ part) {
    int lane = threadIdx.x & 63;
    int t = (blockIdx.x * 256 + threadIdx.x) >> 6;   // 0..10239
    int vr = 2 * t;                                   // virtual row 0..20478
    const f4* X = (const f4*)h + lane;
    f4 xx[10];
#pragma unroll
    for (int k = 0; k < 10; k++) xx[k] = X[k * 64];
    const f4* B = ((vr < FFN_) ? (const f4*)Wg + (size_t)vr * 640
                               : (const f4*)Wu + (size_t)(vr - FFN_) * 640) + lane;
    f4 wv[20];
#pragma unroll
    for (int k = 0; k < 20; k++) wv[k] = __builtin_nontemporal_load(B + k * 64);
    float d0 = 0.f, d1 = 0.f;
#pragma unroll
    for (int k = 0; k < 10; k++)
        d0 += wv[k].x * xx[k].x + wv[k].y * xx[k].y + wv[k].z * xx[k].z + wv[k].w * xx[k].w;
#pragma unroll
    for (int k = 0; k < 10; k++)
        d1 += wv[10 + k].x * xx[k].x + wv[10 + k].y * xx[k].y + wv[10 + k].z * xx[k].z + wv[10 + k].w * xx[k].w;
#pragma unroll
    for (int o = 32; o > 0; o >>= 1) {
        d0 += __shfl_down(d0, o, 64);
        d1 += __shfl_down(d1, o, 64);
    }
    if (lane == 0) {
        part[vr] = d0;
        part[vr + 1] = d1;
    }
}

// ---- gu[i] = gelu(part[i]) * part[FFN+i] ----
__global__ __launch_bounds__(256) void k_gelu_fuse(const float* __restrict__ part,
                                                   float* __restrict__ gu) {
    int i = blockIdx.x * 256 + threadIdx.x;
    float g = part[i], u = part[FFN_ + i];
    float tt = tanhf(0.7978845608028654f * (g + 0.044715f * g * g * g));
    gu[i] = 0.5f * g * (1.f + tt) * u;
}

// ---- Wd: half-row per wave (20 KB contiguous), 2 batches {x preload, W burst} ----
__global__ __launch_bounds__(256) void k_wd(const float* __restrict__ Wd,
                                            const float* __restrict__ gu,
                                            float* __restrict__ part) {
    int lane = threadIdx.x & 63;
    int t = (blockIdx.x * 256 + threadIdx.x) >> 6;   // task: row*2+half
    int half = t & 1;
    const f4* Wr = (const f4*)Wd + (size_t)t * 1280 + lane;
    const f4* Xp = (const f4*)gu + half * 1280 + lane;
    float acc = 0.f;
#pragma unroll
    for (int b = 0; b < 2; b++) {
        f4 xx[10], wv[10];
#pragma unroll
        for (int j = 0; j < 10; j++) xx[j] = Xp[(b * 10 + j) * 64];
#pragma unroll
        for (int j = 0; j < 10; j++)
            wv[j] = __builtin_nontemporal_load(Wr + (b * 10 + j) * 64);
#pragma unroll
        for (int j = 0; j < 10; j++)
            acc += wv[j].x * xx[j].x + wv[j].y * xx[j].y + wv[j].z * xx[j].z + wv[j].w * xx[j].w;
    }
    acc = wave_red_sum(acc);
    if (lane == 0) part[t] = acc;
}

// out1 = (res?) res + rms(a)*(1+w1);  a[i] = sum_{s<slots} apart[i*slots+s]
__global__ __launch_bounds__(512) void k_res_rms(const float* __restrict__ res,
                                                 const float* __restrict__ apart, int slots,
                                                 const float* __restrict__ w1, float* __restrict__ out1,
                                                 const float* __restrict__ w2, float* __restrict__ out2) {
    const int K = D_ / 512;
    int t = threadIdx.x;
    float va[K];
    float ss = 0.f;
#pragma unroll
    for (int k = 0; k < K; k++) {
        int i = t + k * 512;
        float v = 0.f;
        for (int s = 0; s < slots; s++) v += apart[(size_t)i * slots + s];
        va[k] = v;
        ss += v * v;
    }
    float tot = block_red_sum<8>(ss);
    float rs = rsqrtf(tot / (float)D_ + EPSF);
    float vo[K];
    float ss2 = 0.f;
#pragma unroll
    for (int k = 0; k < K; k++) {
        int i = t + k * 512;
        float r = res ? res[i] : 0.f;
        vo[k] = r + va[k] * rs * (1.f + w1[i]);
        out1[i] = vo[k];
        ss2 += vo[k] * vo[k];
    }
    if (out2) {
        float tot2 = block_red_sum<8>(ss2);
        float rs2 = rsqrtf(tot2 / (float)D_ + EPSF);
#pragma unroll
        for (int k = 0; k < K; k++) {
            int i = t + k * 512;
            out2[i] = vo[k] * rs2 * (1.f + w2[i]);
        }
    }
}

// ---- flash-decode partial: one block per (kvh, 32-row chunk).  512 blocks.
__global__ __launch_bounds__(256) void k_attn_part(const float* __restrict__ Kc,
                                                   const float* __restrict__ V,
                                                   const float* __restrict__ qraw,
                                                   const float* __restrict__ cosv,
                                                   const float* __restrict__ sinv,
                                                   const float* __restrict__ mask,
                                                   float* __restrict__ pm,
                                                   float* __restrict__ pl,
                                                   float* __restrict__ pacc) {
    constexpr int RW = CTX_ / ACH;   // 32 rows per chunk, 8 per wave
    int kvh = blockIdx.x, ch = blockIdx.y;
    int lane = threadIdx.x & 63, w = threadIdx.x >> 6;
    int t = threadIdx.x;
    int h0 = 2 * kvh, h1 = h0 + 1;
    int l0 = ch * RW;
    __shared__ float s0[RW], s1[RW];
    __shared__ f4 pv0[4][64], pv1[4][64];

    const f4* q4 = (const f4*)qraw;
    f4 qr0 = q4[h0 * 64 + lane];
    f4 qr1 = q4[h1 * 64 + lane];
    float n0 = wave_red_sum_b(qr0.x * qr0.x + qr0.y * qr0.y + qr0.z * qr0.z + qr0.w * qr0.w);
    float n1 = wave_red_sum_b(qr1.x * qr1.x + qr1.y * qr1.y + qr1.z * qr1.z + qr1.w * qr1.w);
    f4 qn0 = qr0 * rsqrtf(n0 / (float)HD_ + EPSF);
    f4 qn1 = qr1 * rsqrtf(n1 / (float)HD_ + EPSF);
    f4 p0, p1;
    p0.x = __shfl_xor(qn0.x, 32, 64); p0.y = __shfl_xor(qn0.y, 32, 64);
    p0.z = __shfl_xor(qn0.z, 32, 64); p0.w = __shfl_xor(qn0.w, 32, 64);
    p1.x = __shfl_xor(qn1.x, 32, 64); p1.y = __shfl_xor(qn1.y, 32, 64);
    p1.z = __shfl_xor(qn1.z, 32, 64); p1.w = __shfl_xor(qn1.w, 32, 64);
    f4 rot0 = (lane < 32) ? -p0 : p0;
    f4 rot1 = (lane < 32) ? -p1 : p1;
    f4 cs = ((const f4*)cosv)[lane];
    f4 sn = ((const f4*)sinv)[lane];
    f4 q0 = qn0 * cs + rot0 * sn;
    f4 q1 = qn1 * cs + rot1 * sn;

    const f4* Kb = (const f4*)Kc + ((size_t)kvh * CTX_ + l0 + w * 8) * 64 + lane;
    f4 kk[8];
#pragma unroll
    for (int i = 0; i < 8; i++) kk[i] = Kb[i * 64];
    float d0[8], d1[8];
#pragma unroll
    for (int i = 0; i < 8; i++) {
        d0[i] = kk[i].x * q0.x + kk[i].y * q0.y + kk[i].z * q0.z + kk[i].w * q0.w;
        d1[i] = kk[i].x * q1.x + kk[i].y * q1.y + kk[i].z * q1.z + kk[i].w * q1.w;
    }
#pragma unroll
    for (int o = 32; o > 0; o >>= 1) {
#pragma unroll
        for (int i = 0; i < 8; i++) {
            d0[i] += __shfl_down(d0[i], o, 64);
            d1[i] += __shfl_down(d1[i], o, 64);
        }
    }
    if (lane == 0) {
#pragma unroll
        for (int i = 0; i < 8; i++) {
            float m = mask[l0 + w * 8 + i];
            s0[w * 8 + i] = d0[i] + m;
            s1[w * 8 + i] = d1[i] + m;
        }
    }
    __syncthreads();

    float m0 = block_red_max<4>(t < RW ? s0[t] : -3e38f);
    float m1 = block_red_max<4>(t < RW ? s1[t] : -3e38f);
    float e0 = 0.f, e1 = 0.f;
    if (t < RW) {
        e0 = expf(s0[t] - m0); s0[t] = e0;
        e1 = expf(s1[t] - m1); s1[t] = e1;
    }
    float l0sum = block_red_sum<4>(e0);
    float l1sum = block_red_sum<4>(e1);

    const f4* Vb = (const f4*)V + ((size_t)kvh * CTX_ + l0 + w * 8) * 64 + lane;
    f4 vv[8];
#pragma unroll
    for (int i = 0; i < 8; i++) vv[i] = Vb[i * 64];
    f4 a0 = {0.f, 0.f, 0.f, 0.f}, a1 = {0.f, 0.f, 0.f, 0.f};
#pragma unroll
    for (int i = 0; i < 8; i++) {
        a0 += vv[i] * s0[w * 8 + i];
        a1 += vv[i] * s1[w * 8 + i];
    }
    pv0[w][lane] = a0;
    pv1[w][lane] = a1;
    __syncthreads();
    const float* f0 = (const float*)pv0;
    const float* f1 = (const float*)pv1;
    float r0 = f0[t] + f0[256 + t] + f0[512 + t] + f0[768 + t];
    float r1 = f1[t] + f1[256 + t] + f1[512 + t] + f1[768 + t];
    pacc[((size_t)(h0 * ACH) + ch) * HD_ + t] = r0;
    pacc[((size_t)(h1 * ACH) + ch) * HD_ + t] = r1;
    if (t == 0) {
        pm[h0 * ACH + ch] = m0; pl[h0 * ACH + ch] = l0sum;
        pm[h1 * ACH + ch] = m1; pl[h1 * ACH + ch] = l1sum;
    }
}

// ---- combine: grid = NH_, thread = d ----
__global__ __launch_bounds__(256) void k_attn_comb(const float* __restrict__ pm,
                                                   const float* __restrict__ pl,
                                                   const float* __restrict__ pacc,
                                                   float* __restrict__ a) {
    int h = blockIdx.x, t = threadIdx.x;
    __shared__ float wgt[ACH];
    float M = block_red_max<4>(t < ACH ? pm[h * ACH + t] : -3e38f);
    float lw = 0.f;
    if (t < ACH) {
        float wv = expf(pm[h * ACH + t] - M);
        wgt[t] = wv;
        lw = wv * pl[h * ACH + t];
    }
    float L = block_red_sum<4>(lw);
    float acc = 0.f;
    const float* pb = pacc + (size_t)h * ACH * HD_ + t;
#pragma unroll 8
    for (int c = 0; c < ACH; c++) acc += wgt[c] * pb[(size_t)c * HD_];
    a[h * HD_ + t] = acc / L;
}

extern "C" void kernel_launch(void* const* d_in, const int* in_sizes, int n_in,
                              void* d_out, int out_size, void* d_ws, size_t ws_size,
                              hipStream_t stream) {
    const float* x     = (const float*)d_in[0];
    const float* cosv  = (const float*)d_in[1];
    const float* sinv  = (const float*)d_in[2];
    const float* mask  = (const float*)d_in[3];
    const float* cK    = (const float*)d_in[4];
    const float* cV    = (const float*)d_in[5];
    const float* w_in  = (const float*)d_in[7];
    const float* w_pa  = (const float*)d_in[8];
    const float* w_pf  = (const float*)d_in[9];
    const float* w_pff = (const float*)d_in[10];
    const float* Wq    = (const float*)d_in[11];
    const float* Wo    = (const float*)d_in[12];
    const float* Wg    = (const float*)d_in[13];
    const float* Wu    = (const float*)d_in[14];
    const float* Wd    = (const float*)d_in[15];

    float* ws    = (float*)d_ws;
    float* qraw  = ws;             // 2048
    float* pm    = ws + 2048;      // 1024
    float* pl    = ws + 3072;      // 1024
    float* pacc  = ws + 4096;      // 262144
    float* a     = ws + 266240;    // 2048
    float* ao    = ws + 268288;    // 2560
    float* x2    = ws + 270848;    // 2560
    float* h2    = ws + 273408;    // 2560
    float* gu    = ws + 275968;    // 10240
    float* partg = ws + 286208;    // 2*FFN = 20480
    float* partd = ws + 306688;    // 5120
    float* out   = (float*)d_out;

    // qraw = rmsnorm(x,w_in) @ Wq.T  (fused)
    k_wq_fused<<<QD_ / 4, 256, 0, stream>>>(Wq, x, w_in, qraw);
    // attention: flash-decode partials + combine
    k_attn_part<<<dim3(NKV_, ACH), 256, 0, stream>>>(cK, cV, qraw, cosv, sinv,
                                                     mask, pm, pl, pacc);
    k_attn_comb<<<NH_, 256, 0, stream>>>(pm, pl, pacc, a);
    // ao = a @ Wo.T
    k_gemv_row<8><<<D_ / 4, 256, 0, stream>>>(Wo, a, ao);
    // x2 = x + rms(ao)*(1+w_pa);  h2 = rms(x2)*(1+w_pf)
    k_res_rms<<<1, 512, 0, stream>>>(x, ao, 1, w_pa, x2, w_pf, h2);
    // g/u partials: 2 adjacent rows of one matrix per wave (20 KB contiguous)
    k_gg2<<<2 * FFN_ / 2 / 4, 256, 0, stream>>>(Wg, Wu, h2, partg);
    k_gelu_fuse<<<FFN_ / 256, 256, 0, stream>>>(partg, gu);
    // ffn partials = gu @ Wd.T (20 KB contiguous half-rows)
    k_wd<<<D_ * 2 / 4, 256, 0, stream>>>(Wd, gu, partd);
    // out = x2 + rms(sum partd)*(1+w_pff)
    k_res_rms<<<1, 512, 0, stream>>>(x2, partd, 2, w_pff, out, nullptr, nullptr);
}

// Round 16
// 89.722 us; speedup vs baseline: 1.5970x; 1.0579x over previous
//
#include <hip/hip_runtime.h>

#define D_    2560
#define NH_   8
#define NKV_  4
#define HD_   256
#define FFN_  10240
#define QD_   2048
#define CTX_  4096
#define EPSF  1e-6f
#define ACH   128   // attention chunks per kv head (32 rows each)

typedef float f4 __attribute__((ext_vector_type(4)));

// XCD-aware block swizzle: give each XCD a contiguous slab of tasks.
// nwg must be divisible by 8 (all our grids are).
__device__ __forceinline__ int swz_block(int bid, int nwg) {
    int per = nwg >> 3;
    return (bid & 7) * per + (bid >> 3);
}

__device__ __forceinline__ float wave_red_sum(float v) {
#pragma unroll
    for (int o = 32; o > 0; o >>= 1) v += __shfl_down(v, o, 64);
    return v;
}

// butterfly: result in ALL lanes
__device__ __forceinline__ float wave_red_sum_b(float v) {
#pragma unroll
    for (int o = 32; o > 0; o >>= 1) v += __shfl_xor(v, o, 64);
    return v;
}

template <int NW>
__device__ __forceinline__ float block_red_sum(float v) {
    __shared__ float s[NW];
    __shared__ float tot;
    int lane = threadIdx.x & 63, w = threadIdx.x >> 6;
    v = wave_red_sum(v);
    if (lane == 0) s[w] = v;
    __syncthreads();
    if (threadIdx.x == 0) {
        float t = 0.f;
#pragma unroll
        for (int i = 0; i < NW; i++) t += s[i];
        tot = t;
    }
    __syncthreads();
    return tot;
}

template <int NW>
__device__ __forceinline__ float block_red_max(float v) {
    __shared__ float s[NW];
    __shared__ float tot;
    int lane = threadIdx.x & 63, w = threadIdx.x >> 6;
#pragma unroll
    for (int o = 32; o > 0; o >>= 1) v = fmaxf(v, __shfl_down(v, o, 64));
    if (lane == 0) s[w] = v;
    __syncthreads();
    if (threadIdx.x == 0) {
        float t = -3e38f;
#pragma unroll
        for (int i = 0; i < NW; i++) t = fmaxf(t, s[i]);
        tot = t;
    }
    __syncthreads();
    return tot;
}

// ---- Wq GEMV with inline rmsnorm(x, w_in), XCD-swizzled rows ----
__global__ __launch_bounds__(256) void k_wq_fused(const float* __restrict__ Wq,
                                                  const float* __restrict__ x,
                                                  const float* __restrict__ w_in,
                                                  float* __restrict__ qraw) {
    int lane = threadIdx.x & 63;
    int row = swz_block(blockIdx.x, gridDim.x) * 4 + (threadIdx.x >> 6);
    const f4* X = (const f4*)x + lane;
    const f4* WI = (const f4*)w_in + lane;
    f4 xx[10], wi[10];
#pragma unroll
    for (int k = 0; k < 10; k++) xx[k] = X[k * 64];
#pragma unroll
    for (int k = 0; k < 10; k++) wi[k] = WI[k * 64];
    const f4* Wr = (const f4*)Wq + (size_t)row * 640 + lane;
    f4 wv[10];
#pragma unroll
    for (int k = 0; k < 10; k++) wv[k] = __builtin_nontemporal_load(Wr + k * 64);
    float ss = 0.f;
#pragma unroll
    for (int k = 0; k < 10; k++)
        ss += xx[k].x * xx[k].x + xx[k].y * xx[k].y + xx[k].z * xx[k].z + xx[k].w * xx[k].w;
    ss = wave_red_sum_b(ss);
    float rs = rsqrtf(ss / (float)D_ + EPSF);
    float acc = 0.f;
#pragma unroll
    for (int k = 0; k < 10; k++) {
        f4 hh = xx[k] * rs * (1.f + wi[k]);
        acc += wv[k].x * hh.x + wv[k].y * hh.y + wv[k].z * hh.z + wv[k].w * hh.w;
    }
    acc = wave_red_sum(acc);
    if (lane == 0) qraw[row] = acc;
}

// ---- GEMV: x preloaded before W burst, XCD-swizzled rows ----
template <int CPL>
__global__ __launch_bounds__(256) void k_gemv_row(const float* __restrict__ W,
                                                  const float* __restrict__ x,
                                                  float* __restrict__ y) {
    int lane = threadIdx.x & 63;
    int row = swz_block(blockIdx.x, gridDim.x) * 4 + (threadIdx.x >> 6);
    const f4* X = (const f4*)x + lane;
    f4 xx[CPL];
#pragma unroll
    for (int k = 0; k < CPL; k++) xx[k] = X[k * 64];
    const f4* Wr = (const f4*)W + (size_t)row * (CPL * 64) + lane;
    f4 wv[CPL];
#pragma unroll
    for (int k = 0; k < CPL; k++) wv[k] = __builtin_nontemporal_load(Wr + k * 64);
    float acc = 0.f;
#pragma unroll
    for (int k = 0; k < CPL; k++)
        acc += wv[k].x * xx[k].x + wv[k].y * xx[k].y + wv[k].z * xx[k].z + wv[k].w * xx[k].w;
    acc = wave_red_sum(acc);
    if (lane == 0) y[row] = acc;
}

// ---- fused GeGLU (R11 shape: plain loads, dual pointer), XCD-swizzled ----
__global__ __launch_bounds__(256) void k_geglu(const float* __restrict__ Wg,
                                               const float* __restrict__ Wu,
                                               const float* __restrict__ h,
                                               float* __restrict__ gu) {
    int lane = threadIdx.x & 63;
    int row = swz_block(blockIdx.x, gridDim.x) * 4 + (threadIdx.x >> 6);
    const f4* X = (const f4*)h + lane;
    f4 xx[10];
#pragma unroll
    for (int k = 0; k < 10; k++) xx[k] = X[k * 64];
    const f4* G = (const f4*)Wg + (size_t)row * 640 + lane;
    const f4* U = (const f4*)Wu + (size_t)row * 640 + lane;
    f4 wg[10], wu[10];
#pragma unroll
    for (int k = 0; k < 10; k++) wg[k] = G[k * 64];
#pragma unroll
    for (int k = 0; k < 10; k++) wu[k] = U[k * 64];
    float ag = 0.f, au = 0.f;
#pragma unroll
    for (int k = 0; k < 10; k++)
        ag += wg[k].x * xx[k].x + wg[k].y * xx[k].y + wg[k].z * xx[k].z + wg[k].w * xx[k].w;
#pragma unroll
    for (int k = 0; k < 10; k++)
        au += wu[k].x * xx[k].x + wu[k].y * xx[k].y + wu[k].z * xx[k].z + wu[k].w * xx[k].w;
#pragma unroll
    for (int o = 32; o > 0; o >>= 1) {
        ag += __shfl_down(ag, o, 64);
        au += __shfl_down(au, o, 64);
    }
    if (lane == 0) {
        float g = ag;
        float tt = tanhf(0.7978845608028654f * (g + 0.044715f * g * g * g));
        gu[row] = 0.5f * g * (1.f + tt) * au;
    }
}

// ---- Wd: half-row per wave, nt weights, XCD-swizzled tasks ----
__global__ __launch_bounds__(256) void k_wd(const float* __restrict__ Wd,
                                            const float* __restrict__ gu,
                                            float* __restrict__ part) {
    int lane = threadIdx.x & 63;
    int t = swz_block(blockIdx.x, gridDim.x) * 4 + (threadIdx.x >> 6);  // row*2+half
    int half = t & 1;
    const f4* Wr = (const f4*)Wd + (size_t)t * 1280 + lane;
    const f4* Xp = (const f4*)gu + half * 1280 + lane;
    float acc = 0.f;
#pragma unroll
    for (int b = 0; b < 2; b++) {
        f4 xx[10], wv[10];
#pragma unroll
        for (int j = 0; j < 10; j++) xx[j] = Xp[(b * 10 + j) * 64];
#pragma unroll
        for (int j = 0; j < 10; j++)
            wv[j] = __builtin_nontemporal_load(Wr + (b * 10 + j) * 64);
#pragma unroll
        for (int j = 0; j < 10; j++)
            acc += wv[j].x * xx[j].x + wv[j].y * xx[j].y + wv[j].z * xx[j].z + wv[j].w * xx[j].w;
    }
    acc = wave_red_sum(acc);
    if (lane == 0) part[t] = acc;
}

// out1 = (res?) res + rms(a)*(1+w1);  a[i] = sum_{s<slots} apart[i*slots+s]
__global__ __launch_bounds__(512) void k_res_rms(const float* __restrict__ res,
                                                 const float* __restrict__ apart, int slots,
                                                 const float* __restrict__ w1, float* __restrict__ out1,
                                                 const float* __restrict__ w2, float* __restrict__ out2) {
    const int K = D_ / 512;
    int t = threadIdx.x;
    float va[K];
    float ss = 0.f;
#pragma unroll
    for (int k = 0; k < K; k++) {
        int i = t + k * 512;
        float v = 0.f;
        for (int s = 0; s < slots; s++) v += apart[(size_t)i * slots + s];
        va[k] = v;
        ss += v * v;
    }
    float tot = block_red_sum<8>(ss);
    float rs = rsqrtf(tot / (float)D_ + EPSF);
    float vo[K];
    float ss2 = 0.f;
#pragma unroll
    for (int k = 0; k < K; k++) {
        int i = t + k * 512;
        float r = res ? res[i] : 0.f;
        vo[k] = r + va[k] * rs * (1.f + w1[i]);
        out1[i] = vo[k];
        ss2 += vo[k] * vo[k];
    }
    if (out2) {
        float tot2 = block_red_sum<8>(ss2);
        float rs2 = rsqrtf(tot2 / (float)D_ + EPSF);
#pragma unroll
        for (int k = 0; k < K; k++) {
            int i = t + k * 512;
            out2[i] = vo[k] * rs2 * (1.f + w2[i]);
        }
    }
}

// ---- flash-decode partial: one block per (kvh, 32-row chunk).  512 blocks.
__global__ __launch_bounds__(256) void k_attn_part(const float* __restrict__ Kc,
                                                   const float* __restrict__ V,
                                                   const float* __restrict__ qraw,
                                                   const float* __restrict__ cosv,
                                                   const float* __restrict__ sinv,
                                                   const float* __restrict__ mask,
                                                   float* __restrict__ pm,
                                                   float* __restrict__ pl,
                                                   float* __restrict__ pacc) {
    constexpr int RW = CTX_ / ACH;   // 32 rows per chunk, 8 per wave
    int kvh = blockIdx.x, ch = blockIdx.y;
    int lane = threadIdx.x & 63, w = threadIdx.x >> 6;
    int t = threadIdx.x;
    int h0 = 2 * kvh, h1 = h0 + 1;
    int l0 = ch * RW;
    __shared__ float s0[RW], s1[RW];
    __shared__ f4 pv0[4][64], pv1[4][64];

    const f4* q4 = (const f4*)qraw;
    f4 qr0 = q4[h0 * 64 + lane];
    f4 qr1 = q4[h1 * 64 + lane];
    float n0 = wave_red_sum_b(qr0.x * qr0.x + qr0.y * qr0.y + qr0.z * qr0.z + qr0.w * qr0.w);
    float n1 = wave_red_sum_b(qr1.x * qr1.x + qr1.y * qr1.y + qr1.z * qr1.z + qr1.w * qr1.w);
    f4 qn0 = qr0 * rsqrtf(n0 / (float)HD_ + EPSF);
    f4 qn1 = qr1 * rsqrtf(n1 / (float)HD_ + EPSF);
    f4 p0, p1;
    p0.x = __shfl_xor(qn0.x, 32, 64); p0.y = __shfl_xor(qn0.y, 32, 64);
    p0.z = __shfl_xor(qn0.z, 32, 64); p0.w = __shfl_xor(qn0.w, 32, 64);
    p1.x = __shfl_xor(qn1.x, 32, 64); p1.y = __shfl_xor(qn1.y, 32, 64);
    p1.z = __shfl_xor(qn1.z, 32, 64); p1.w = __shfl_xor(qn1.w, 32, 64);
    f4 rot0 = (lane < 32) ? -p0 : p0;
    f4 rot1 = (lane < 32) ? -p1 : p1;
    f4 cs = ((const f4*)cosv)[lane];
    f4 sn = ((const f4*)sinv)[lane];
    f4 q0 = qn0 * cs + rot0 * sn;
    f4 q1 = qn1 * cs + rot1 * sn;

    const f4* Kb = (const f4*)Kc + ((size_t)kvh * CTX_ + l0 + w * 8) * 64 + lane;
    f4 kk[8];
#pragma unroll
    for (int i = 0; i < 8; i++) kk[i] = Kb[i * 64];
    float d0[8], d1[8];
#pragma unroll
    for (int i = 0; i < 8; i++) {
        d0[i] = kk[i].x * q0.x + kk[i].y * q0.y + kk[i].z * q0.z + kk[i].w * q0.w;
        d1[i] = kk[i].x * q1.x + kk[i].y * q1.y + kk[i].z * q1.z + kk[i].w * q1.w;
    }
#pragma unroll
    for (int o = 32; o > 0; o >>= 1) {
#pragma unroll
        for (int i = 0; i < 8; i++) {
            d0[i] += __shfl_down(d0[i], o, 64);
            d1[i] += __shfl_down(d1[i], o, 64);
        }
    }
    if (lane == 0) {
#pragma unroll
        for (int i = 0; i < 8; i++) {
            float m = mask[l0 + w * 8 + i];
            s0[w * 8 + i] = d0[i] + m;
            s1[w * 8 + i] = d1[i] + m;
        }
    }
    __syncthreads();

    float m0 = block_red_max<4>(t < RW ? s0[t] : -3e38f);
    float m1 = block_red_max<4>(t < RW ? s1[t] : -3e38f);
    float e0 = 0.f, e1 = 0.f;
    if (t < RW) {
        e0 = expf(s0[t] - m0); s0[t] = e0;
        e1 = expf(s1[t] - m1); s1[t] = e1;
    }
    float l0sum = block_red_sum<4>(e0);
    float l1sum = block_red_sum<4>(e1);

    const f4* Vb = (const f4*)V + ((size_t)kvh * CTX_ + l0 + w * 8) * 64 + lane;
    f4 vv[8];
#pragma unroll
    for (int i = 0; i < 8; i++) vv[i] = Vb[i * 64];
    f4 a0 = {0.f, 0.f, 0.f, 0.f}, a1 = {0.f, 0.f, 0.f, 0.f};
#pragma unroll
    for (int i = 0; i < 8; i++) {
        a0 += vv[i] * s0[w * 8 + i];
        a1 += vv[i] * s1[w * 8 + i];
    }
    pv0[w][lane] = a0;
    pv1[w][lane] = a1;
    __syncthreads();
    const float* f0 = (const float*)pv0;
    const float* f1 = (const float*)pv1;
    float r0 = f0[t] + f0[256 + t] + f0[512 + t] + f0[768 + t];
    float r1 = f1[t] + f1[256 + t] + f1[512 + t] + f1[768 + t];
    pacc[((size_t)(h0 * ACH) + ch) * HD_ + t] = r0;
    pacc[((size_t)(h1 * ACH) + ch) * HD_ + t] = r1;
    if (t == 0) {
        pm[h0 * ACH + ch] = m0; pl[h0 * ACH + ch] = l0sum;
        pm[h1 * ACH + ch] = m1; pl[h1 * ACH + ch] = l1sum;
    }
}

// ---- combine: grid = NH_, thread = d ----
__global__ __launch_bounds__(256) void k_attn_comb(const float* __restrict__ pm,
                                                   const float* __restrict__ pl,
                                                   const float* __restrict__ pacc,
                                                   float* __restrict__ a) {
    int h = blockIdx.x, t = threadIdx.x;
    __shared__ float wgt[ACH];
    float M = block_red_max<4>(t < ACH ? pm[h * ACH + t] : -3e38f);
    float lw = 0.f;
    if (t < ACH) {
        float wv = expf(pm[h * ACH + t] - M);
        wgt[t] = wv;
        lw = wv * pl[h * ACH + t];
    }
    float L = block_red_sum<4>(lw);
    float acc = 0.f;
    const float* pb = pacc + (size_t)h * ACH * HD_ + t;
#pragma unroll 8
    for (int c = 0; c < ACH; c++) acc += wgt[c] * pb[(size_t)c * HD_];
    a[h * HD_ + t] = acc / L;
}

extern "C" void kernel_launch(void* const* d_in, const int* in_sizes, int n_in,
                              void* d_out, int out_size, void* d_ws, size_t ws_size,
                              hipStream_t stream) {
    const float* x     = (const float*)d_in[0];
    const float* cosv  = (const float*)d_in[1];
    const float* sinv  = (const float*)d_in[2];
    const float* mask  = (const float*)d_in[3];
    const float* cK    = (const float*)d_in[4];
    const float* cV    = (const float*)d_in[5];
    const float* w_in  = (const float*)d_in[7];
    const float* w_pa  = (const float*)d_in[8];
    const float* w_pf  = (const float*)d_in[9];
    const float* w_pff = (const float*)d_in[10];
    const float* Wq    = (const float*)d_in[11];
    const float* Wo    = (const float*)d_in[12];
    const float* Wg    = (const float*)d_in[13];
    const float* Wu    = (const float*)d_in[14];
    const float* Wd    = (const float*)d_in[15];

    float* ws    = (float*)d_ws;
    float* qraw  = ws;             // 2048
    float* pm    = ws + 2048;      // 1024
    float* pl    = ws + 3072;      // 1024
    float* pacc  = ws + 4096;      // 262144
    float* a     = ws + 266240;    // 2048
    float* ao    = ws + 268288;    // 2560
    float* x2    = ws + 270848;    // 2560
    float* h2    = ws + 273408;    // 2560
    float* gu    = ws + 275968;    // 10240
    float* partd = ws + 286208;    // 5120
    float* out   = (float*)d_out;

    // qraw = rmsnorm(x,w_in) @ Wq.T  (fused, XCD-swizzled)
    k_wq_fused<<<QD_ / 4, 256, 0, stream>>>(Wq, x, w_in, qraw);
    // attention: flash-decode partials + combine
    k_attn_part<<<dim3(NKV_, ACH), 256, 0, stream>>>(cK, cV, qraw, cosv, sinv,
                                                     mask, pm, pl, pacc);
    k_attn_comb<<<NH_, 256, 0, stream>>>(pm, pl, pacc, a);
    // ao = a @ Wo.T  (XCD-swizzled)
    k_gemv_row<8><<<D_ / 4, 256, 0, stream>>>(Wo, a, ao);
    // x2 = x + rms(ao)*(1+w_pa);  h2 = rms(x2)*(1+w_pf)
    k_res_rms<<<1, 512, 0, stream>>>(x, ao, 1, w_pa, x2, w_pf, h2);
    // gu = gelu(h2@Wg.T) * (h2@Wu.T)  (fused, XCD-swizzled)
    k_geglu<<<FFN_ / 4, 256, 0, stream>>>(Wg, Wu, h2, gu);
    // ffn partials = gu @ Wd.T  (XCD-swizzled)
    k_wd<<<D_ * 2 / 4, 256, 0, stream>>>(Wd, gu, partd);
    // out = x2 + rms(sum partd)*(1+w_pff)
    k_res_rms<<<1, 512, 0, stream>>>(x2, partd, 2, w_pff, out, nullptr, nullptr);
}